// Round 3
// baseline (1740.408 us; speedup 1.0000x reference)
//
#include <hip/hip_runtime.h>
#include <hip/hip_bf16.h>
#include <stdint.h>

typedef unsigned short u16;
typedef unsigned int u32;

typedef __attribute__((__ext_vector_type__(8))) short short8;
typedef __attribute__((__ext_vector_type__(4))) float float4v;

typedef const u32 __attribute__((address_space(1))) gu32;
typedef u32 __attribute__((address_space(3))) lu32;

__device__ __forceinline__ u16 f2b(float f) {
  __hip_bfloat16 h = __float2bfloat16(f);
  return *reinterpret_cast<u16*>(&h);
}

// async global->LDS, 16B per lane; LDS dest = wave-uniform base + lane*16
__device__ __forceinline__ void gld16(const void* g, void* l) {
  __builtin_amdgcn_global_load_lds((gu32*)g, (lu32*)l, 16, 0, 0);
}

// ---------------- adj fp32 -> bf16 ----------------
__global__ __launch_bounds__(256) void k_cvt(const float* __restrict__ a, u16* __restrict__ o) {
  int t = blockIdx.x * 256 + threadIdx.x;
  float4 v0 = ((const float4*)a)[2 * t];
  float4 v1 = ((const float4*)a)[2 * t + 1];
  u16 r[8];
  r[0] = f2b(v0.x); r[1] = f2b(v0.y); r[2] = f2b(v0.z); r[3] = f2b(v0.w);
  r[4] = f2b(v1.x); r[5] = f2b(v1.y); r[6] = f2b(v1.z); r[7] = f2b(v1.w);
  ((uint4*)o)[t] = *(const uint4*)r;
}

// ---------------- mask + stats zero (fp32 in, fp32 out + bf16 H) ----------------
__global__ __launch_bounds__(256) void k_mask(
    const float* __restrict__ x, const float* __restrict__ msk, const float* __restrict__ nz,
    u16* __restrict__ H, float* __restrict__ oxm, float* __restrict__ omask, float* __restrict__ ST)
{
  int t = blockIdx.x * 256 + threadIdx.x;
  if (blockIdx.x == 0) {
#pragma unroll
    for (int k = 0; k < 10; ++k) ST[threadIdx.x + k * 256] = 0.f;
  }
  float xv[8], mv[8], nv[8], rv[8];
  *(float4*)&xv[0] = ((const float4*)x)[2 * t];
  *(float4*)&xv[4] = ((const float4*)x)[2 * t + 1];
  *(float4*)&mv[0] = ((const float4*)msk)[2 * t];
  *(float4*)&mv[4] = ((const float4*)msk)[2 * t + 1];
  *(float4*)&nv[0] = ((const float4*)nz)[2 * t];
  *(float4*)&nv[4] = ((const float4*)nz)[2 * t + 1];
  u16 res[8];
#pragma unroll
  for (int j = 0; j < 8; ++j) {
    rv[j] = xv[j] * (1.f - mv[j]) + nv[j] * mv[j];
    res[j] = f2b(rv[j]);
  }
  ((uint4*)H)[t] = *(const uint4*)res;
  ((float4*)oxm)[2 * t]     = *(const float4*)&rv[0];
  ((float4*)oxm)[2 * t + 1] = *(const float4*)&rv[4];
  ((float4*)omask)[2 * t]     = *(const float4*)&mv[0];
  ((float4*)omask)[2 * t + 1] = *(const float4*)&mv[4];
}

// ---------------- small matmul: Tt[d][i] = sum_e W[e][d] * H[i][e] ----------------
// A[m=d][k=e] = W[e][d] (fp32 -> bf16), B[k=e][n=i] = H[i][e] (bf16)
__global__ __launch_bounds__(256) void k_mm1(
    const u16* __restrict__ H, const float* __restrict__ W, u16* __restrict__ Tt)
{
  __shared__ __align__(16) u16 Wl[128 * 136]; // [d][e], pad +8 shorts
  __shared__ __align__(16) u16 Hl[128 * 136]; // [i][e], pad +8 shorts
  const int tid = threadIdx.x;
  const int w = tid >> 6, lane = tid & 63;
  const int ln = lane & 15, quad = lane >> 4;
  const int i0 = blockIdx.x * 128;

#pragma unroll
  for (int it = 0; it < 16; ++it) { // stage W transposed, cvt fp32->bf16
    int idx4 = (it * 256 + tid) * 4;
    int e = idx4 >> 7, d0 = idx4 & 127;
    float4 v = *(const float4*)(W + idx4);
    Wl[(d0 + 0) * 136 + e] = f2b(v.x);
    Wl[(d0 + 1) * 136 + e] = f2b(v.y);
    Wl[(d0 + 2) * 136 + e] = f2b(v.z);
    Wl[(d0 + 3) * 136 + e] = f2b(v.w);
  }
#pragma unroll
  for (int it = 0; it < 8; ++it) { // stage H tile row-major (bf16)
    int chunk = tid + it * 256;
    int r = chunk >> 4, c8 = (chunk & 15) * 8;
    uint4 v = *(const uint4*)(H + (size_t)(i0 + r) * 128 + c8);
    *(uint4*)(&Hl[r * 136 + c8]) = v;
  }
  __syncthreads();

  float4v acc[2][8] = {};
#pragma unroll
  for (int ks = 0; ks < 4; ++ks) {
    short8 a[2], b[8];
#pragma unroll
    for (int r = 0; r < 2; ++r)
      a[r] = *(const short8*)&Wl[(w * 32 + r * 16 + ln) * 136 + ks * 32 + quad * 8];
#pragma unroll
    for (int c = 0; c < 8; ++c)
      b[c] = *(const short8*)&Hl[(c * 16 + ln) * 136 + ks * 32 + quad * 8];
#pragma unroll
    for (int r = 0; r < 2; ++r)
#pragma unroll
      for (int c = 0; c < 8; ++c)
        acc[r][c] = __builtin_amdgcn_mfma_f32_16x16x32_bf16(a[r], b[c], acc[r][c], 0, 0, 0);
  }
#pragma unroll
  for (int r = 0; r < 2; ++r)
#pragma unroll
    for (int c = 0; c < 8; ++c)
#pragma unroll
      for (int g = 0; g < 4; ++g) {
        int d = w * 32 + r * 16 + quad * 4 + g;   // C/D: row = quad*4+reg
        int i = i0 + c * 16 + ln;                 // C/D: col = lane&15
        Tt[(size_t)d * 8192 + i] = f2b(acc[r][c][g]);
      }
}

// ---------------- big matmul: OUT[i][d] = sum_k adj[i][k]*T[k][d] (+bias,prelu,stats) ----
// 32x128 tile, BK=64, double-buffered LDS, chunked layout [koct][row][16B]
template <bool LAST, bool AF32>
__global__ __launch_bounds__(256) void k_mm2(
    const u16* __restrict__ adjB, const float* __restrict__ adjF, const u16* __restrict__ Tt,
    const float* __restrict__ bias, const float* __restrict__ alphaP,
    float* __restrict__ ACT, float* __restrict__ ST, float* __restrict__ outL)
{
  __shared__ __align__(16) char smem[40960]; // 2 buffers x (A 4KB + B 16KB)
  const int tid = threadIdx.x;
  const int w = tid >> 6, lane = tid & 63;
  const int ln = lane & 15, quad = lane >> 4;
  const int i0 = blockIdx.x * 32;

  // per-lane global staging sources (advance 64 K-elements per step)
  const char* gA = nullptr;      // bf16 path
  const float* gAf = nullptr;    // fp32 path
  const char* gB[4];
  {
    int ca = tid;                      // A chunk id: koct = ca>>5, m = ca&31
    int ko = ca >> 5, m = ca & 31;
    if (AF32) gAf = adjF + (size_t)(i0 + m) * 8192 + ko * 8;
    else      gA  = (const char*)(adjB + (size_t)(i0 + m) * 8192 + ko * 8);
#pragma unroll
    for (int j = 0; j < 4; ++j) {      // B chunk id: koct = cb>>7, n = cb&127
      int cb = (w * 4 + j) * 64 + lane;
      int kob = cb >> 7, n = cb & 127;
      gB[j] = (const char*)(Tt + (size_t)n * 8192 + kob * 8);
    }
  }
  float4v acc[2][2] = {};

  auto stage = [&](int buf) {
    char* base = smem + buf * 20480;
    if (AF32) {
      float4 u0 = *(const float4*)gAf;
      float4 u1 = *(const float4*)(gAf + 4);
      u16 r[8];
      r[0] = f2b(u0.x); r[1] = f2b(u0.y); r[2] = f2b(u0.z); r[3] = f2b(u0.w);
      r[4] = f2b(u1.x); r[5] = f2b(u1.y); r[6] = f2b(u1.z); r[7] = f2b(u1.w);
      *(uint4*)(base + tid * 16) = *(const uint4*)r;
      gAf += 64;
    } else {
      gld16(gA, base + (tid >> 6) * 1024 + (tid & 63) * 16);
      gA += 128;
    }
#pragma unroll
    for (int j = 0; j < 4; ++j) {
      gld16(gB[j], base + 4096 + (w * 4 + j) * 1024 + (lane) * 16);
      gB[j] += 128;
    }
  };

  stage(0);
  __syncthreads();

  for (int s = 0; s < 128; ++s) {
    int buf = s & 1;
    if (s < 127) stage(buf ^ 1);
    const char* base = smem + buf * 20480;
#pragma unroll
    for (int ks = 0; ks < 2; ++ks) {
      int ko = ks * 4 + quad;
      short8 a0 = *(const short8*)(base + ((ko * 32) + ln) * 16);
      short8 a1 = *(const short8*)(base + ((ko * 32) + 16 + ln) * 16);
      short8 b0 = *(const short8*)(base + 4096 + ((ko * 128) + w * 32 + ln) * 16);
      short8 b1 = *(const short8*)(base + 4096 + ((ko * 128) + w * 32 + 16 + ln) * 16);
      acc[0][0] = __builtin_amdgcn_mfma_f32_16x16x32_bf16(a0, b0, acc[0][0], 0, 0, 0);
      acc[0][1] = __builtin_amdgcn_mfma_f32_16x16x32_bf16(a0, b1, acc[0][1], 0, 0, 0);
      acc[1][0] = __builtin_amdgcn_mfma_f32_16x16x32_bf16(a1, b0, acc[1][0], 0, 0, 0);
      acc[1][1] = __builtin_amdgcn_mfma_f32_16x16x32_bf16(a1, b1, acc[1][1], 0, 0, 0);
    }
    __syncthreads();
  }

  const float alpha = alphaP[0];
#pragma unroll
  for (int c = 0; c < 2; ++c) {
    const int d = w * 32 + c * 16 + ln;
    const float bb = bias[d];
    float s1 = 0.f, s2 = 0.f;
#pragma unroll
    for (int r = 0; r < 2; ++r)
#pragma unroll
      for (int g = 0; g < 4; ++g) {
        int i = i0 + r * 16 + quad * 4 + g;
        float u = acc[r][c][g] + bb;
        float a = (u >= 0.f) ? u : alpha * u;
        if (LAST) {
          outL[(size_t)i * 128 + d] = a;
        } else {
          ACT[(size_t)i * 128 + d] = a;
          s1 += a; s2 += a * a;
        }
      }
    if (!LAST) {
      s1 += __shfl_xor(s1, 16); s1 += __shfl_xor(s1, 32);
      s2 += __shfl_xor(s2, 16); s2 += __shfl_xor(s2, 32);
      if (quad == 0) {
        atomicAdd(ST + d, s1);
        atomicAdd(ST + 128 + d, s2);
      }
    }
  }
}

// ---------------- BN apply: H = bf16(gamma*(ACT-mu)*rsqrt(var+eps)+beta), out2 fp32 ------
__global__ __launch_bounds__(256) void k_bn(
    const float* __restrict__ ACT, const float* __restrict__ ST,
    const float* __restrict__ gamma, const float* __restrict__ beta,
    u16* __restrict__ H, float* __restrict__ out2)
{
  int t = blockIdx.x * 256 + threadIdx.x;
  int base = t * 4;
  int d0 = base & 127;
  float4 a = *(const float4*)(ACT + base);
  const float* ap = (const float*)&a;
  float rv[4];
  u16 res[4];
#pragma unroll
  for (int j = 0; j < 4; ++j) {
    int d = d0 + j;
    float mu = ST[d] * (1.f / 8192.f);
    float var = ST[128 + d] * (1.f / 8192.f) - mu * mu;
    float sc = gamma[d] * rsqrtf(var + 1e-5f);
    float sh = beta[d] - mu * sc;
    rv[j] = ap[j] * sc + sh;
    res[j] = f2b(rv[j]);
  }
  *(uint2*)(H + base) = *(const uint2*)res;
  if (out2) *(float4*)(out2 + base) = *(const float4*)rv;
}

extern "C" void kernel_launch(void* const* d_in, const int* in_sizes, int n_in,
                              void* d_out, int out_size, void* d_ws, size_t ws_size,
                              hipStream_t stream)
{
  const float* x     = (const float*)d_in[0];
  const float* adj   = (const float*)d_in[1];
  const float* msk   = (const float*)d_in[2];
  const float* nz    = (const float*)d_in[3];
  const float* encW  = (const float*)d_in[4];
  const float* encB  = (const float*)d_in[5];
  const float* encA  = (const float*)d_in[6];
  const float* encG  = (const float*)d_in[7];
  const float* encBe = (const float*)d_in[8];
  const float* decW  = (const float*)d_in[9];
  const float* decB  = (const float*)d_in[10];
  const float* decA  = (const float*)d_in[11];
  const float* decG  = (const float*)d_in[12];
  const float* decBe = (const float*)d_in[13];

  const bool big = ws_size >= 142616576ull;
  char* ws = (char*)d_ws;
  u16*   adjB = big ? (u16*)ws : nullptr;                    // 128 MB bf16 adj
  char*  base = big ? ws + 134217728ull : ws;
  u16*   H   = (u16*)base;                                   // 2 MB [8192][128] bf16
  u16*   Tt  = (u16*)(base + 2097152);                       // 2 MB [128][8192] bf16
  float* ACT = (float*)(base + 4194304);                     // 4 MB [8192][128] f32
  float* ST  = (float*)(base + 8388608);                     // 10 KB stats

  float* out   = (float*)d_out;
  float* o_xm  = out;
  float* o_enc = out + 1048576;
  float* o_dec = out + 2097152;
  float* o_msk = out + 3145728;

  if (big) k_cvt<<<32768, 256, 0, stream>>>(adj, adjB);
  k_mask<<<512, 256, 0, stream>>>(x, msk, nz, H, o_xm, o_msk, ST);

  for (int l = 0; l < 10; ++l) {
    bool e = l < 5;
    int li = e ? l : l - 5;
    const float* W  = (e ? encW : decW) + li * 16384;
    const float* bb = (e ? encB : decB) + li * 128;
    const float* al = (e ? encA : decA) + li;
    const float* gg = (e ? encG : decG) + li * 128;
    const float* be = (e ? encBe : decBe) + li * 128;
    float* st = ST + l * 256;

    k_mm1<<<64, 256, 0, stream>>>(H, W, Tt);
    if (l == 9) {
      if (big) k_mm2<true, false><<<256, 256, 0, stream>>>(adjB, nullptr, Tt, bb, al, nullptr, nullptr, o_dec);
      else     k_mm2<true, true ><<<256, 256, 0, stream>>>(nullptr, adj, Tt, bb, al, nullptr, nullptr, o_dec);
    } else {
      if (big) k_mm2<false, false><<<256, 256, 0, stream>>>(adjB, nullptr, Tt, bb, al, ACT, st, nullptr);
      else     k_mm2<false, true ><<<256, 256, 0, stream>>>(nullptr, adj, Tt, bb, al, ACT, st, nullptr);
      k_bn<<<1024, 256, 0, stream>>>(ACT, st, gg, be, H, (l == 4) ? o_enc : nullptr);
    }
  }
}

// Round 5
// 956.935 us; speedup vs baseline: 1.8187x; 1.8187x over previous
//
#include <hip/hip_runtime.h>
#include <hip/hip_bf16.h>
#include <stdint.h>

typedef unsigned short u16;
typedef unsigned int u32;

typedef __attribute__((__ext_vector_type__(8))) short short8;
typedef __attribute__((__ext_vector_type__(4))) float float4v;
typedef __attribute__((__ext_vector_type__(16))) float float16v;

typedef const u32 __attribute__((address_space(1))) gu32;
typedef u32 __attribute__((address_space(3))) lu32;

__device__ __forceinline__ u16 f2b(float f) {
  __hip_bfloat16 h = __float2bfloat16(f);
  return *reinterpret_cast<u16*>(&h);
}

// async global->LDS, 16B per lane; LDS dest = wave-uniform base + lane*16
__device__ __forceinline__ void gld16(const void* g, void* l) {
  __builtin_amdgcn_global_load_lds((gu32*)g, (lu32*)l, 16, 0, 0);
}

// ---------------- adj fp32 -> bf16 ----------------
__global__ __launch_bounds__(256) void k_cvt(const float* __restrict__ a, u16* __restrict__ o) {
  int t = blockIdx.x * 256 + threadIdx.x;
  float4 v0 = ((const float4*)a)[2 * t];
  float4 v1 = ((const float4*)a)[2 * t + 1];
  u16 r[8];
  r[0] = f2b(v0.x); r[1] = f2b(v0.y); r[2] = f2b(v0.z); r[3] = f2b(v0.w);
  r[4] = f2b(v1.x); r[5] = f2b(v1.y); r[6] = f2b(v1.z); r[7] = f2b(v1.w);
  ((uint4*)o)[t] = *(const uint4*)r;
}

// ---------------- mask + stats zero (fp32 in, fp32 out + bf16 H i-major) ----------------
__global__ __launch_bounds__(256) void k_mask(
    const float* __restrict__ x, const float* __restrict__ msk, const float* __restrict__ nz,
    u16* __restrict__ H, float* __restrict__ oxm, float* __restrict__ omask, float* __restrict__ ST)
{
  int t = blockIdx.x * 256 + threadIdx.x;
  if (blockIdx.x == 0) {
#pragma unroll
    for (int k = 0; k < 10; ++k) ST[threadIdx.x + k * 256] = 0.f;
  }
  float xv[8], mv[8], nv[8], rv[8];
  *(float4*)&xv[0] = ((const float4*)x)[2 * t];
  *(float4*)&xv[4] = ((const float4*)x)[2 * t + 1];
  *(float4*)&mv[0] = ((const float4*)msk)[2 * t];
  *(float4*)&mv[4] = ((const float4*)msk)[2 * t + 1];
  *(float4*)&nv[0] = ((const float4*)nz)[2 * t];
  *(float4*)&nv[4] = ((const float4*)nz)[2 * t + 1];
  u16 res[8];
#pragma unroll
  for (int j = 0; j < 8; ++j) {
    rv[j] = xv[j] * (1.f - mv[j]) + nv[j] * mv[j];
    res[j] = f2b(rv[j]);
  }
  ((uint4*)H)[t] = *(const uint4*)res;
  ((float4*)oxm)[2 * t]     = *(const float4*)&rv[0];
  ((float4*)oxm)[2 * t + 1] = *(const float4*)&rv[4];
  ((float4*)omask)[2 * t]     = *(const float4*)&mv[0];
  ((float4*)omask)[2 * t + 1] = *(const float4*)&mv[4];
}

// ---------------- small matmul: Tc = chunked( W^T @ H^T ) ----------------
// Tt[d][i] = sum_e W[e][d] * H[i][e]; Tc layout: [k-chunk kc=i/8][d][8 elems]
// IMAJOR: Hin = H[i][e] (layer 0). else Hin = Ht[e][i] (d^T-major hidden state)
template <bool IMAJOR>
__global__ __launch_bounds__(256) void k_mm1(
    const u16* __restrict__ Hin, const float* __restrict__ W, u16* __restrict__ Tc)
{
  __shared__ __align__(16) u16 Wl[128 * 136]; // [d][e], pad
  __shared__ __align__(16) u16 Hl[128 * 136]; // [i][e], pad
  const int tid = threadIdx.x;
  const int w = tid >> 6, lane = tid & 63;
  const int ln = lane & 15, quad = lane >> 4;
  const int i0 = blockIdx.x * 128;

#pragma unroll
  for (int it = 0; it < 16; ++it) { // stage W transposed, cvt fp32->bf16 (4096 float4s)
    int idx4 = (it * 256 + tid) * 4;
    int e = idx4 >> 7, d0 = idx4 & 127;
    float4 v = *(const float4*)(W + idx4);
    Wl[(d0 + 0) * 136 + e] = f2b(v.x);
    Wl[(d0 + 1) * 136 + e] = f2b(v.y);
    Wl[(d0 + 2) * 136 + e] = f2b(v.z);
    Wl[(d0 + 3) * 136 + e] = f2b(v.w);
  }
  if (IMAJOR) {
#pragma unroll
    for (int it = 0; it < 8; ++it) { // H[i][e] rows -> Hl[i][e] (2048 vec8 chunks)
      int chunk = tid + it * 256;
      int r = chunk >> 4, c8 = (chunk & 15) * 8;
      uint4 v = *(const uint4*)(Hin + (size_t)(i0 + r) * 128 + c8);
      *(uint4*)(&Hl[r * 136 + c8]) = v;
    }
  } else {
#pragma unroll
    for (int it = 0; it < 8; ++it) { // Ht[e][i] rows -> transpose into Hl[i][e]
      int tmp = it * 256 + tid;      // 2048 chunks: e = tmp>>4 in [0,128)
      int e = tmp >> 4, i8 = (tmp & 15) * 8;
      uint4 v = *(const uint4*)(Hin + (size_t)e * 8192 + i0 + i8);
      const u16* pv = (const u16*)&v;
#pragma unroll
      for (int j = 0; j < 8; ++j) Hl[(i8 + j) * 136 + e] = pv[j];
    }
  }
  __syncthreads();

  float4v acc[2][8] = {};
#pragma unroll
  for (int ks = 0; ks < 4; ++ks) {
    short8 a[2], b[8];
#pragma unroll
    for (int r = 0; r < 2; ++r)
      a[r] = *(const short8*)&Wl[(w * 32 + r * 16 + ln) * 136 + ks * 32 + quad * 8];
#pragma unroll
    for (int c = 0; c < 8; ++c)
      b[c] = *(const short8*)&Hl[(c * 16 + ln) * 136 + ks * 32 + quad * 8];
#pragma unroll
    for (int r = 0; r < 2; ++r)
#pragma unroll
      for (int c = 0; c < 8; ++c)
        acc[r][c] = __builtin_amdgcn_mfma_f32_16x16x32_bf16(a[r], b[c], acc[r][c], 0, 0, 0);
  }
#pragma unroll
  for (int r = 0; r < 2; ++r)
#pragma unroll
    for (int c = 0; c < 8; ++c)
#pragma unroll
      for (int g = 0; g < 4; ++g) {
        int d = w * 32 + r * 16 + quad * 4 + g;   // C/D: row = quad*4+reg
        int i = i0 + c * 16 + ln;                 // C/D: col = lane&15
        Tc[((size_t)(i >> 3) * 128 + d) * 8 + (i & 7)] = f2b(acc[r][c][g]);
      }
}

// ---------------- big matmul (transposed): PB[seg][d][i] partial of OUT^T ----------------
// A = Tt (LDS, staged per 256-k sub-seg), B = adj rows (direct per-lane global loads)
// block: 4 waves, tile 128(d) x 256(i), KSEG=1024 (split-K 8), grid 256
__global__ __launch_bounds__(256, 1) void k_gemm(
    const u16* __restrict__ adjB, const u16* __restrict__ Tc, float* __restrict__ PB)
{
  __shared__ __align__(16) u16 Al[2][32 * 128 * 8];  // 2 x 64 KB, chunked [lc][d][8]
  const int tid = threadIdx.x;
  const int w = tid >> 6, lane = tid & 63;
  const int lrow = lane & 31, lhalf = lane >> 5;
  const int nt = blockIdx.x >> 3, seg = blockIdx.x & 7;
  const int i0 = nt * 256;

  // B pointers: wave w covers i in [i0+w*64, +64); frag rows are adj rows (k-contig)
  const u16* bp0 = adjB + (size_t)(i0 + w * 64 + lrow) * 8192 + seg * 1024 + lhalf * 8;
  const u16* bp1 = bp0 + (size_t)32 * 8192;

  float16v acc[4][2] = {};

  auto stage = [&](int p, int ss) {
    const u16* src = Tc + ((size_t)(seg * 128 + ss * 32) * 128 + tid) * 8;
    u16* dst = &Al[p][tid * 8];
#pragma unroll
    for (int c = 0; c < 16; ++c)
      gld16(src + c * 2048, dst + c * 2048);   // fully coalesced 4 KB per call
  };

  auto compute = [&](int p) {
#pragma unroll 4
    for (int t = 0; t < 16; ++t) {
      short8 b0 = *(const short8*)(bp0 + t * 16);
      short8 b1 = *(const short8*)(bp1 + t * 16);
      short8 a[4];
#pragma unroll
      for (int dm = 0; dm < 4; ++dm)
        a[dm] = *(const short8*)&Al[p][((t * 2 + lhalf) * 128 + dm * 32 + lrow) * 8];
#pragma unroll
      for (int dm = 0; dm < 4; ++dm) {
        acc[dm][0] = __builtin_amdgcn_mfma_f32_32x32x16_bf16(a[dm], b0, acc[dm][0], 0, 0, 0);
        acc[dm][1] = __builtin_amdgcn_mfma_f32_32x32x16_bf16(a[dm], b1, acc[dm][1], 0, 0, 0);
      }
    }
    bp0 += 256; bp1 += 256;
  };

  stage(0, 0);
  __syncthreads();
#pragma unroll
  for (int ss = 0; ss < 4; ++ss) {
    if (ss < 3) stage((ss & 1) ^ 1, ss + 1);
    compute(ss & 1);
    __syncthreads();
  }

  // epilogue: C/D 32x32 layout: col(i)=lane&31, row(d)=(g&3)+8*(g>>2)+4*(lane>>5)
  const int ib = i0 + w * 64 + lrow;
#pragma unroll
  for (int dm = 0; dm < 4; ++dm)
#pragma unroll
    for (int nb = 0; nb < 2; ++nb)
#pragma unroll
      for (int g = 0; g < 16; ++g) {
        int d = dm * 32 + (g & 3) + 8 * (g >> 2) + 4 * lhalf;
        PB[((size_t)seg * 128 + d) * 8192 + ib + nb * 32] = acc[dm][nb][g];
      }
}

// ---------------- reduce partials + bias + prelu (+stats) ----------------
// grid 256: blockIdx = d*2 + half; row-major everything (coalesced)
template <bool LAST>
__global__ __launch_bounds__(256) void k_red(
    const float* __restrict__ PB, const float* __restrict__ bias, const float* __restrict__ alphaP,
    float* __restrict__ ACTt, float* __restrict__ ST, float* __restrict__ outL)
{
  const int d = blockIdx.x >> 1, half = blockIdx.x & 1;
  const int tid = threadIdx.x;
  const float bb = bias[d], alpha = alphaP[0];
  const float* pb = PB + (size_t)d * 8192 + half * 4096;
  float s1 = 0.f, s2 = 0.f;
#pragma unroll
  for (int it = 0; it < 4; ++it) {
    int idx = it * 1024 + tid * 4;
    float4 v = *(const float4*)(pb + idx);
#pragma unroll
    for (int s = 1; s < 8; ++s) {
      float4 u = *(const float4*)(pb + (size_t)s * 1048576 + idx);
      v.x += u.x; v.y += u.y; v.z += u.z; v.w += u.w;
    }
    float r[4];
    const float* vp = (const float*)&v;
#pragma unroll
    for (int j = 0; j < 4; ++j) {
      float u = vp[j] + bb;
      r[j] = (u >= 0.f) ? u : alpha * u;
    }
    if (LAST) {
      int i = half * 4096 + idx;
#pragma unroll
      for (int j = 0; j < 4; ++j) outL[(size_t)(i + j) * 128 + d] = r[j];
    } else {
      *(float4*)(ACTt + (size_t)d * 8192 + half * 4096 + idx) = *(const float4*)r;
#pragma unroll
      for (int j = 0; j < 4; ++j) { s1 += r[j]; s2 += r[j] * r[j]; }
    }
  }
  if (!LAST) {
#pragma unroll
    for (int off = 1; off < 64; off <<= 1) {
      s1 += __shfl_xor(s1, off);
      s2 += __shfl_xor(s2, off);
    }
    __shared__ float red[8];
    if ((tid & 63) == 0) { red[(tid >> 6) * 2] = s1; red[(tid >> 6) * 2 + 1] = s2; }
    __syncthreads();
    if (tid == 0) {
      atomicAdd(ST + d, red[0] + red[2] + red[4] + red[6]);
      atomicAdd(ST + 128 + d, red[1] + red[3] + red[5] + red[7]);
    }
  }
}

// ---------------- BN apply (transposed domain): Ht = bf16(sc*ACTt+sh) ----------------
__global__ __launch_bounds__(256) void k_bn(
    const float* __restrict__ ACTt, const float* __restrict__ ST,
    const float* __restrict__ gamma, const float* __restrict__ beta,
    u16* __restrict__ Ht, float* __restrict__ out2)
{
  int d = blockIdx.x >> 3;
  int i = (blockIdx.x & 7) * 1024 + threadIdx.x * 4;
  float mu = ST[d] * (1.f / 8192.f);
  float var = ST[128 + d] * (1.f / 8192.f) - mu * mu;
  float sc = gamma[d] * rsqrtf(var + 1e-5f);
  float sh = beta[d] - mu * sc;
  float4 v = *(const float4*)(ACTt + (size_t)d * 8192 + i);
  float r[4] = {v.x * sc + sh, v.y * sc + sh, v.z * sc + sh, v.w * sc + sh};
  u16 res[4] = {f2b(r[0]), f2b(r[1]), f2b(r[2]), f2b(r[3])};
  *(uint2*)(Ht + (size_t)d * 8192 + i) = *(const uint2*)res;
  if (out2) {
#pragma unroll
    for (int j = 0; j < 4; ++j) out2[(size_t)(i + j) * 128 + d] = r[j];
  }
}

extern "C" void kernel_launch(void* const* d_in, const int* in_sizes, int n_in,
                              void* d_out, int out_size, void* d_ws, size_t ws_size,
                              hipStream_t stream)
{
  const float* x     = (const float*)d_in[0];
  const float* adj   = (const float*)d_in[1];
  const float* msk   = (const float*)d_in[2];
  const float* nz    = (const float*)d_in[3];
  const float* encW  = (const float*)d_in[4];
  const float* encB  = (const float*)d_in[5];
  const float* encA  = (const float*)d_in[6];
  const float* encG  = (const float*)d_in[7];
  const float* encBe = (const float*)d_in[8];
  const float* decW  = (const float*)d_in[9];
  const float* decB  = (const float*)d_in[10];
  const float* decA  = (const float*)d_in[11];
  const float* decG  = (const float*)d_in[12];
  const float* decBe = (const float*)d_in[13];

  char* ws = (char*)d_ws;
  u16*   adjB = (u16*)ws;                         // 128 MB bf16 adj
  u16*   Tc   = (u16*)(ws + 134217728ull);        // 2 MB chunked T^T
  u16*   Ht   = (u16*)(ws + 136314880ull);        // 2 MB bf16 [128][8192]
  u16*   H    = (u16*)(ws + 138412032ull);        // 2 MB bf16 [8192][128] (layer 0)
  float* ACTt = (float*)(ws + 140509184ull);      // 4 MB fp32 [128][8192]
  float* PB   = (float*)(ws + 144703488ull);      // 32 MB fp32 [8][128][8192]
  float* ST   = (float*)(ws + 178257920ull);      // 10 KB stats

  float* out   = (float*)d_out;
  float* o_xm  = out;
  float* o_enc = out + 1048576;
  float* o_dec = out + 2097152;
  float* o_msk = out + 3145728;

  k_cvt<<<32768, 256, 0, stream>>>(adj, adjB);
  k_mask<<<512, 256, 0, stream>>>(x, msk, nz, H, o_xm, o_msk, ST);

  for (int l = 0; l < 10; ++l) {
    bool e = l < 5;
    int li = e ? l : l - 5;
    const float* W  = (e ? encW : decW) + li * 16384;
    const float* bb = (e ? encB : decB) + li * 128;
    const float* al = (e ? encA : decA) + li;
    const float* gg = (e ? encG : decG) + li * 128;
    const float* be = (e ? encBe : decBe) + li * 128;
    float* st = ST + l * 256;

    if (l == 0) k_mm1<true ><<<64, 256, 0, stream>>>(H,  W, Tc);
    else        k_mm1<false><<<64, 256, 0, stream>>>(Ht, W, Tc);

    k_gemm<<<256, 256, 0, stream>>>(adjB, Tc, PB);

    if (l == 9) {
      k_red<true><<<256, 256, 0, stream>>>(PB, bb, al, nullptr, nullptr, o_dec);
    } else {
      k_red<false><<<256, 256, 0, stream>>>(PB, bb, al, ACTt, st, nullptr);
      k_bn<<<1024, 256, 0, stream>>>(ACTt, st, gg, be, Ht, (l == 4) ? o_enc : nullptr);
    }
  }
}